// Round 10
// baseline (142.461 us; speedup 1.0000x reference)
//
#include <hip/hip_runtime.h>
#include <math.h>

// Problem sizes (fixed by the reference)
#define B   4
#define TQ  256
#define TV  1024
#define D   512
#define A   128

#define LOG2E     1.4426950408889634f
#define TWO_LOG2E 2.8853900817779268f
#define NEG_BIG_F (-1e9f)

#define QBLK (B * TQ / 8)   // 128 q-projection blocks
#define KBLK (B * TV / 8)   // 512 k-projection blocks

// ---------------------------------------------------------------------------
// Fused projection + exp(2x) for BOTH q and k.
//   q path: Eq[r, a]     = exp(2*(ctx[r,:]@Wq[:,a] + bq[a]))   [row-major]
//   k path: EkT[b, a, v] = exp(2*(inp[r,:]@Wk[:,a] + bk[a]))   [TRANSPOSED]
// Block = 256 thr (4 waves). d-split is PER-WAVE (g = tid>>6, wave-uniform
// by construction -- round 9's bug was readfirstlane on tid>>5, which is NOT
// uniform within a wave): wave g owns d in [g*128, g*128+128). All 64 lanes
// share X addresses -> s_load_dwordx4 (scalar cache; no LDS pipe, no VMEM).
// Lane owns an a-PAIR (float2 of W, coalesced 8B/lane) x 8 rows = 16 acc;
// 64 FMA per 4-d unit. 4 wave partials reduced through 16 KB LDS.
// ---------------------------------------------------------------------------
__global__ __launch_bounds__(256, 4) void proj_exp_kernel(
    const float* __restrict__ ctx, const float* __restrict__ inp,
    const float* __restrict__ Wq, const float* __restrict__ bq,
    const float* __restrict__ Wk, const float* __restrict__ bk,
    float* __restrict__ Eq, float* __restrict__ EkT) {
  __shared__ float ps[8][4][A];     // 16 KB (row j, wave, a)
  __shared__ float es[A][9];        // 4.6 KB (transpose staging, +1 pad)

  bool isQ = blockIdx.x < QBLK;
  const float* X; const float* W; const float* bias; int r0;
  if (isQ) { X = ctx; W = Wq; bias = bq; r0 = blockIdx.x * 8; }
  else     { X = inp; W = Wk; bias = bk; r0 = (blockIdx.x - QBLK) * 8; }

  int tid = threadIdx.x;
  int ap = (tid & 63) * 2;      // a-pair base: 64 lanes cover a = 0..127
  int g  = tid >> 6;            // wave id 0..3  (wave-uniform)

  // dbase is uniform across the wave -> readfirstlane is a legal SGPR force.
  int dbase = __builtin_amdgcn_readfirstlane(g * 128);
  const float* Xr = X + (size_t)r0 * D + dbase;   // wave-uniform base
  const float* Wd = W + (size_t)dbase * A + ap;

  float2 acc[8];
#pragma unroll
  for (int j = 0; j < 8; ++j) acc[j] = make_float2(0.f, 0.f);

#pragma unroll 2
  for (int dd = 0; dd < 128; dd += 4) {
    float2 w0 = *(const float2*)(Wd + (size_t)(dd + 0) * A);
    float2 w1 = *(const float2*)(Wd + (size_t)(dd + 1) * A);
    float2 w2 = *(const float2*)(Wd + (size_t)(dd + 2) * A);
    float2 w3 = *(const float2*)(Wd + (size_t)(dd + 3) * A);
    float4 x[8];
#pragma unroll
    for (int j = 0; j < 8; ++j)
      x[j] = *(const float4*)(Xr + (size_t)j * D + dd);   // scalar s_load
#pragma unroll
    for (int j = 0; j < 8; ++j) {
      acc[j].x = fmaf(x[j].x, w0.x, acc[j].x);
      acc[j].y = fmaf(x[j].x, w0.y, acc[j].y);
      acc[j].x = fmaf(x[j].y, w1.x, acc[j].x);
      acc[j].y = fmaf(x[j].y, w1.y, acc[j].y);
      acc[j].x = fmaf(x[j].z, w2.x, acc[j].x);
      acc[j].y = fmaf(x[j].z, w2.y, acc[j].y);
      acc[j].x = fmaf(x[j].w, w3.x, acc[j].x);
      acc[j].y = fmaf(x[j].w, w3.y, acc[j].y);
    }
  }

  // write per-wave partials (each lane: 8 rows x its a-pair)
#pragma unroll
  for (int j = 0; j < 8; ++j)
    *(float2*)&ps[j][g][ap] = acc[j];
  __syncthreads();

  // finalize: thread -> (row j, a-quad a4); sum 4 wave partials + bias + exp
  int j  = tid >> 5;            // 0..7
  int a4 = (tid & 31) * 4;
  float4 p0 = *(const float4*)&ps[j][0][a4];
  float4 p1 = *(const float4*)&ps[j][1][a4];
  float4 p2 = *(const float4*)&ps[j][2][a4];
  float4 p3 = *(const float4*)&ps[j][3][a4];
  float4 bz = *(const float4*)(bias + a4);
  float4 ev;
  ev.x = __builtin_amdgcn_exp2f((((p0.x + p1.x) + (p2.x + p3.x)) + bz.x) * TWO_LOG2E);
  ev.y = __builtin_amdgcn_exp2f((((p0.y + p1.y) + (p2.y + p3.y)) + bz.y) * TWO_LOG2E);
  ev.z = __builtin_amdgcn_exp2f((((p0.z + p1.z) + (p2.z + p3.z)) + bz.z) * TWO_LOG2E);
  ev.w = __builtin_amdgcn_exp2f((((p0.w + p1.w) + (p2.w + p3.w)) + bz.w) * TWO_LOG2E);

  if (isQ) {
    *(float4*)(Eq + (size_t)(r0 + j) * A + a4) = ev;   // coalesced per row
  } else {
    es[a4 + 0][j] = ev.x;
    es[a4 + 1][j] = ev.y;
    es[a4 + 2][j] = ev.z;
    es[a4 + 3][j] = ev.w;
    __syncthreads();
    int b  = r0 >> 10;          // TV == 1024
    int v0 = r0 & (TV - 1);
    for (int i = tid; i < A * 8; i += 256) {
      int aa = i >> 3, jj = i & 7;
      EkT[((size_t)b * A + aa) * TV + v0 + jj] = es[aa][jj];
    }
  }
}

// ---------------------------------------------------------------------------
// Scores + softmax: TWO q rows per block, 256 threads (4 waves), 512 blocks
// -> 2 blocks/CU, 8 waves/CU. Thread owns 4 consecutive v for both rows
// (8 independent rcp chains per EkT float4 load). Prefetch distance 2.
//   score[v] = sumV - 2 * sum_a v_a / (Eq[a]*EkT[a,v] + 1)
// ---------------------------------------------------------------------------
__global__ __launch_bounds__(256, 4) void score_softmax_kernel(
    const float* __restrict__ Eq, const float* __restrict__ EkT,
    const float* __restrict__ attn_v, const int* __restrict__ mask,
    float* __restrict__ attn) {
  __shared__ float redA[4], redB[4];
  __shared__ float bc[4];

  int tid = threadIdx.x;
  int v0  = (tid & 63) * 4 + (tid >> 6) * 256;  // wave-contiguous float4
  int r0  = blockIdx.x * 2;
  int b   = r0 >> 8;               // TQ == 256

  const float* eqA = Eq + (size_t)r0 * A;
  const float* eqB = eqA + A;

  float sumV = 0.f;
#pragma unroll 16
  for (int i = 0; i < A; ++i) sumV += attn_v[i];

  const float* ekb = EkT + (size_t)b * A * TV + v0;
  float4 tA = make_float4(0.f, 0.f, 0.f, 0.f);
  float4 tB = make_float4(0.f, 0.f, 0.f, 0.f);

  float4 e0 = *(const float4*)(ekb);
  float4 e1 = *(const float4*)(ekb + (size_t)TV);
#pragma unroll 4
  for (int i = 0; i < A; ++i) {
    float4 en;
    if (i < A - 2) en = *(const float4*)(ekb + (size_t)(i + 2) * TV);
    float av = attn_v[i];
    float qa = eqA[i];
    float qb = eqB[i];
    tA.x = fmaf(av, __builtin_amdgcn_rcpf(fmaf(e0.x, qa, 1.f)), tA.x);
    tA.y = fmaf(av, __builtin_amdgcn_rcpf(fmaf(e0.y, qa, 1.f)), tA.y);
    tA.z = fmaf(av, __builtin_amdgcn_rcpf(fmaf(e0.z, qa, 1.f)), tA.z);
    tA.w = fmaf(av, __builtin_amdgcn_rcpf(fmaf(e0.w, qa, 1.f)), tA.w);
    tB.x = fmaf(av, __builtin_amdgcn_rcpf(fmaf(e0.x, qb, 1.f)), tB.x);
    tB.y = fmaf(av, __builtin_amdgcn_rcpf(fmaf(e0.y, qb, 1.f)), tB.y);
    tB.z = fmaf(av, __builtin_amdgcn_rcpf(fmaf(e0.z, qb, 1.f)), tB.z);
    tB.w = fmaf(av, __builtin_amdgcn_rcpf(fmaf(e0.w, qb, 1.f)), tB.w);
    e0 = e1;
    e1 = en;
  }

  int4 mk = *(const int4*)(mask + b * TV + v0);
  float4 sA, sB;
  sA.x = sumV - 2.f * tA.x + (1.f - (float)mk.x) * NEG_BIG_F;
  sA.y = sumV - 2.f * tA.y + (1.f - (float)mk.y) * NEG_BIG_F;
  sA.z = sumV - 2.f * tA.z + (1.f - (float)mk.z) * NEG_BIG_F;
  sA.w = sumV - 2.f * tA.w + (1.f - (float)mk.w) * NEG_BIG_F;
  sB.x = sumV - 2.f * tB.x + (1.f - (float)mk.x) * NEG_BIG_F;
  sB.y = sumV - 2.f * tB.y + (1.f - (float)mk.y) * NEG_BIG_F;
  sB.z = sumV - 2.f * tB.z + (1.f - (float)mk.z) * NEG_BIG_F;
  sB.w = sumV - 2.f * tB.w + (1.f - (float)mk.w) * NEG_BIG_F;

  float mA = fmaxf(fmaxf(sA.x, sA.y), fmaxf(sA.z, sA.w));
  float mB = fmaxf(fmaxf(sB.x, sB.y), fmaxf(sB.z, sB.w));
  for (int off = 32; off > 0; off >>= 1) {
    mA = fmaxf(mA, __shfl_down(mA, off, 64));
    mB = fmaxf(mB, __shfl_down(mB, off, 64));
  }
  int w = tid >> 6;
  if ((tid & 63) == 0) { redA[w] = mA; redB[w] = mB; }
  __syncthreads();
  if (tid == 0) {
    bc[0] = fmaxf(fmaxf(redA[0], redA[1]), fmaxf(redA[2], redA[3]));
    bc[1] = fmaxf(fmaxf(redB[0], redB[1]), fmaxf(redB[2], redB[3]));
  }
  __syncthreads();
  float MA = bc[0], MB = bc[1];

  float4 eAv, eBv;
  eAv.x = __builtin_amdgcn_exp2f((sA.x - MA) * LOG2E);
  eAv.y = __builtin_amdgcn_exp2f((sA.y - MA) * LOG2E);
  eAv.z = __builtin_amdgcn_exp2f((sA.z - MA) * LOG2E);
  eAv.w = __builtin_amdgcn_exp2f((sA.w - MA) * LOG2E);
  eBv.x = __builtin_amdgcn_exp2f((sB.x - MB) * LOG2E);
  eBv.y = __builtin_amdgcn_exp2f((sB.y - MB) * LOG2E);
  eBv.z = __builtin_amdgcn_exp2f((sB.z - MB) * LOG2E);
  eBv.w = __builtin_amdgcn_exp2f((sB.w - MB) * LOG2E);
  float lA = (eAv.x + eAv.y) + (eAv.z + eAv.w);
  float lB = (eBv.x + eBv.y) + (eBv.z + eBv.w);
  for (int off = 32; off > 0; off >>= 1) {
    lA += __shfl_down(lA, off, 64);
    lB += __shfl_down(lB, off, 64);
  }
  __syncthreads();   // protect red[] before rewrite
  if ((tid & 63) == 0) { redA[w] = lA; redB[w] = lB; }
  __syncthreads();
  if (tid == 0) {
    bc[2] = (redA[0] + redA[1]) + (redA[2] + redA[3]);
    bc[3] = (redB[0] + redB[1]) + (redB[2] + redB[3]);
  }
  __syncthreads();
  float iA = 1.f / bc[2];
  float iB = 1.f / bc[3];

  float4 oA = make_float4(eAv.x * iA, eAv.y * iA, eAv.z * iA, eAv.w * iA);
  float4 oB = make_float4(eBv.x * iB, eBv.y * iB, eBv.z * iB, eBv.w * iB);
  *(float4*)(attn + (size_t)r0 * TV + v0)       = oA;
  *(float4*)(attn + (size_t)(r0 + 1) * TV + v0) = oB;
}

// ---------------------------------------------------------------------------
// out[b,q,:] = sum_v attn[b,q,v] * inputs[b,v,:]   -- NO ATOMICS.
// Block tile: 16 q x 128 d over the FULL v range; v-sum split across the 8
// waves (disjoint 128-v chunks). Thread = (col, qh): 8 q x 4 d = 32 acc;
// per 4-v unit: 4 X float4 VMEM + 8 broadcast-b128 LDS feed 128 FMA.
// Wave partials reduced through the 64 KB LDS buffer, plain coalesced store.
// grid (dt=4, qtile=64) = 256 blocks x 512 thr.
// ---------------------------------------------------------------------------
__global__ __launch_bounds__(512, 2) void pv_kernel(
    const float* __restrict__ attn, const float* __restrict__ X,
    float* __restrict__ out) {
  __shared__ float lds[16 * 1024];   // 64 KB: attn tile, then 8 partial tiles
  int dt = blockIdx.x;               // 0..3, d-slice of 128
  int q0 = blockIdx.y * 16;          // global row (b*TQ + q), 64 tiles
  int b  = q0 >> 8;                  // TQ == 256
  int tid  = threadIdx.x;
  int w    = tid >> 6;               // wave 0..7 -> v range [w*128, ...)
  int lane = tid & 63;
  int col  = lane & 31;              // float4 d-column
  int qh   = lane >> 5;              // 0..1 -> q rows qh*8 .. qh*8+7
  int d0 = dt * 128 + col * 4;

  // stage attn tile: 16 rows x 1024 v = 4096 float4, contiguous, coalesced
  {
    const float4* src = (const float4*)(attn + (size_t)q0 * TV);
    float4* dst = (float4*)lds;
    for (int i = tid; i < 16 * 256; i += 512) dst[i] = src[i];
  }
  __syncthreads();

  float4 acc[8];
#pragma unroll
  for (int j = 0; j < 8; ++j) acc[j] = make_float4(0.f, 0.f, 0.f, 0.f);

  int vbase = w * 128;
  const float* Xb = X + ((size_t)b * TV + vbase) * D + d0;
  const float* arow = &lds[(qh * 8) * 1024 + vbase];  // 8 rows, stride 1024

  float4 xc0 = *(const float4*)(Xb + (size_t)0 * D);
  float4 xc1 = *(const float4*)(Xb + (size_t)1 * D);
  float4 xc2 = *(const float4*)(Xb + (size_t)2 * D);
  float4 xc3 = *(const float4*)(Xb + (size_t)3 * D);

  for (int vi = 0; vi < 128; vi += 4) {
    float4 xn0, xn1, xn2, xn3;
    if (vi < 124) {
      const float* Xn = Xb + (size_t)(vi + 4) * D;
      xn0 = *(const float4*)(Xn + (size_t)0 * D);
      xn1 = *(const float4*)(Xn + (size_t)1 * D);
      xn2 = *(const float4*)(Xn + (size_t)2 * D);
      xn3 = *(const float4*)(Xn + (size_t)3 * D);
    }
#pragma unroll
    for (int j = 0; j < 8; ++j) {
      float4 av = *(const float4*)(arow + j * 1024 + vi);  // 2-addr bcast
      acc[j].x = fmaf(av.x, xc0.x, acc[j].x);
      acc[j].y = fmaf(av.x, xc0.y, acc[j].y);
      acc[j].z = fmaf(av.x, xc0.z, acc[j].z);
      acc[j].w = fmaf(av.x, xc0.w, acc[j].w);
      acc[j].x = fmaf(av.y, xc1.x, acc[j].x);
      acc[j].y = fmaf(av.y, xc1.y, acc[j].y);
      acc[j].z = fmaf(av.y, xc1.z, acc[j].z);
      acc[j].w = fmaf(av.y, xc1.w, acc[j].w);
      acc[j].x = fmaf(av.z, xc2.x, acc[j].x);
      acc[j].y = fmaf(av.z, xc2.y, acc[j].y);
      acc[j].z = fmaf(av.z, xc2.z, acc[j].z);
      acc[j].w = fmaf(av.z, xc2.w, acc[j].w);
      acc[j].x = fmaf(av.w, xc3.x, acc[j].x);
      acc[j].y = fmaf(av.w, xc3.y, acc[j].y);
      acc[j].z = fmaf(av.w, xc3.z, acc[j].z);
      acc[j].w = fmaf(av.w, xc3.w, acc[j].w);
    }
    xc0 = xn0; xc1 = xn1; xc2 = xn2; xc3 = xn3;
  }

  __syncthreads();   // everyone done READING the attn tile

  // write wave partials: lds[w][16 rows][32 float4 cols] (512 f4 per wave)
  {
    float4* pat = (float4*)lds + (size_t)w * 512;
#pragma unroll
    for (int j = 0; j < 8; ++j)
      pat[(qh * 8 + j) * 32 + col] = acc[j];
  }
  __syncthreads();

  // reduce 8 partials and store: 512 float4 outputs, one per thread
  {
    int row = tid >> 5;            // 0..15
    int c   = tid & 31;            // 0..31
    const float4* p = (const float4*)lds + tid;  // == row*32 + c
    float4 r = p[0];
#pragma unroll
    for (int i = 1; i < 8; ++i) {
      float4 t = p[(size_t)i * 512];
      r.x += t.x; r.y += t.y; r.z += t.z; r.w += t.w;
    }
    *(float4*)(out + (size_t)(q0 + row) * D + dt * 128 + c * 4) = r;
  }
}

extern "C" void kernel_launch(void* const* d_in, const int* in_sizes, int n_in,
                              void* d_out, int out_size, void* d_ws, size_t ws_size,
                              hipStream_t stream) {
  const float* inputs  = (const float*)d_in[0];  // [B,TV,D]
  const float* context = (const float*)d_in[1];  // [B,TQ,D]
  const int*   mask    = (const int*)d_in[2];    // [B,TV]
  const float* Wk      = (const float*)d_in[3];  // [D,A]
  const float* bk      = (const float*)d_in[4];  // [A]
  const float* Wq      = (const float*)d_in[5];  // [D,A]
  const float* bq      = (const float*)d_in[6];  // [A]
  const float* attn_v  = (const float*)d_in[7];  // [A]
  float* out = (float*)d_out;                    // [B,TQ,D]

  // Workspace layout (fp32): Eq | EkT | attn  = 0.5MB + 2MB + 4MB
  float* Eq   = (float*)d_ws;             // [B*TQ, A]
  float* EkT  = Eq + B * TQ * A;          // [B, A, TV]  (transposed!)
  float* attn = EkT + (size_t)B * A * TV; // [B*TQ, TV]

  proj_exp_kernel<<<QBLK + KBLK, 256, 0, stream>>>(context, inputs, Wq, bq,
                                                   Wk, bk, Eq, EkT);
  score_softmax_kernel<<<B * TQ / 2, 256, 0, stream>>>(Eq, EkT, attn_v, mask,
                                                       attn);
  pv_kernel<<<dim3(4, 64), 512, 0, stream>>>(attn, inputs, out);
}

// Round 11
// 135.163 us; speedup vs baseline: 1.0540x; 1.0540x over previous
//
#include <hip/hip_runtime.h>
#include <math.h>

// Problem sizes (fixed by the reference)
#define B   4
#define TQ  256
#define TV  1024
#define D   512
#define A   128

#define LOG2E     1.4426950408889634f
#define TWO_LOG2E 2.8853900817779268f
#define NEG_BIG_F (-1e9f)

#define QBLK (B * TQ / 8)   // 128 q-projection blocks
#define KBLK (B * TV / 8)   // 512 k-projection blocks

// ---------------------------------------------------------------------------
// Fused projection + exp(2x) for BOTH q and k.
//   q path: Eq[r, a]     = exp(2*(ctx[r,:]@Wq[:,a] + bq[a]))   [row-major]
//   k path: EkT[b, a, v] = exp(2*(inp[r,:]@Wk[:,a] + bk[a]))   [TRANSPOSED]
// Block = 256 thr (4 waves). d-split is PER-WAVE (g = tid>>6, wave-uniform
// by construction): wave g owns d in [g*128, g*128+128). All 64 lanes share
// X addresses -> s_load_dwordx4 (scalar cache; no LDS pipe, no VMEM).
// Lane owns an a-PAIR (float2 of W, coalesced 8B/lane) x 8 rows = 16 acc.
// ---------------------------------------------------------------------------
__global__ __launch_bounds__(256, 4) void proj_exp_kernel(
    const float* __restrict__ ctx, const float* __restrict__ inp,
    const float* __restrict__ Wq, const float* __restrict__ bq,
    const float* __restrict__ Wk, const float* __restrict__ bk,
    float* __restrict__ Eq, float* __restrict__ EkT) {
  __shared__ float ps[8][4][A];     // 16 KB (row j, wave, a)
  __shared__ float es[A][9];        // 4.6 KB (transpose staging, +1 pad)

  bool isQ = blockIdx.x < QBLK;
  const float* X; const float* W; const float* bias; int r0;
  if (isQ) { X = ctx; W = Wq; bias = bq; r0 = blockIdx.x * 8; }
  else     { X = inp; W = Wk; bias = bk; r0 = (blockIdx.x - QBLK) * 8; }

  int tid = threadIdx.x;
  int ap = (tid & 63) * 2;      // a-pair base: 64 lanes cover a = 0..127
  int g  = tid >> 6;            // wave id 0..3  (wave-uniform)

  int dbase = __builtin_amdgcn_readfirstlane(g * 128);
  const float* Xr = X + (size_t)r0 * D + dbase;   // wave-uniform base
  const float* Wd = W + (size_t)dbase * A + ap;

  float2 acc[8];
#pragma unroll
  for (int j = 0; j < 8; ++j) acc[j] = make_float2(0.f, 0.f);

#pragma unroll 2
  for (int dd = 0; dd < 128; dd += 4) {
    float2 w0 = *(const float2*)(Wd + (size_t)(dd + 0) * A);
    float2 w1 = *(const float2*)(Wd + (size_t)(dd + 1) * A);
    float2 w2 = *(const float2*)(Wd + (size_t)(dd + 2) * A);
    float2 w3 = *(const float2*)(Wd + (size_t)(dd + 3) * A);
    float4 x[8];
#pragma unroll
    for (int j = 0; j < 8; ++j)
      x[j] = *(const float4*)(Xr + (size_t)j * D + dd);   // scalar s_load
#pragma unroll
    for (int j = 0; j < 8; ++j) {
      acc[j].x = fmaf(x[j].x, w0.x, acc[j].x);
      acc[j].y = fmaf(x[j].x, w0.y, acc[j].y);
      acc[j].x = fmaf(x[j].y, w1.x, acc[j].x);
      acc[j].y = fmaf(x[j].y, w1.y, acc[j].y);
      acc[j].x = fmaf(x[j].z, w2.x, acc[j].x);
      acc[j].y = fmaf(x[j].z, w2.y, acc[j].y);
      acc[j].x = fmaf(x[j].w, w3.x, acc[j].x);
      acc[j].y = fmaf(x[j].w, w3.y, acc[j].y);
    }
  }

  // write per-wave partials (each lane: 8 rows x its a-pair)
#pragma unroll
  for (int j = 0; j < 8; ++j)
    *(float2*)&ps[j][g][ap] = acc[j];
  __syncthreads();

  // finalize: thread -> (row j, a-quad a4); sum 4 wave partials + bias + exp
  int j  = tid >> 5;            // 0..7
  int a4 = (tid & 31) * 4;
  float4 p0 = *(const float4*)&ps[j][0][a4];
  float4 p1 = *(const float4*)&ps[j][1][a4];
  float4 p2 = *(const float4*)&ps[j][2][a4];
  float4 p3 = *(const float4*)&ps[j][3][a4];
  float4 bz = *(const float4*)(bias + a4);
  float4 ev;
  ev.x = __builtin_amdgcn_exp2f((((p0.x + p1.x) + (p2.x + p3.x)) + bz.x) * TWO_LOG2E);
  ev.y = __builtin_amdgcn_exp2f((((p0.y + p1.y) + (p2.y + p3.y)) + bz.y) * TWO_LOG2E);
  ev.z = __builtin_amdgcn_exp2f((((p0.z + p1.z) + (p2.z + p3.z)) + bz.z) * TWO_LOG2E);
  ev.w = __builtin_amdgcn_exp2f((((p0.w + p1.w) + (p2.w + p3.w)) + bz.w) * TWO_LOG2E);

  if (isQ) {
    *(float4*)(Eq + (size_t)(r0 + j) * A + a4) = ev;   // coalesced per row
  } else {
    es[a4 + 0][j] = ev.x;
    es[a4 + 1][j] = ev.y;
    es[a4 + 2][j] = ev.z;
    es[a4 + 3][j] = ev.w;
    __syncthreads();
    int b  = r0 >> 10;          // TV == 1024
    int v0 = r0 & (TV - 1);
    for (int i = tid; i < A * 8; i += 256) {
      int aa = i >> 3, jj = i & 7;
      EkT[((size_t)b * A + aa) * TV + v0 + jj] = es[aa][jj];
    }
  }
}

// ---------------------------------------------------------------------------
// Scores + softmax: TWO q rows per block, 512 threads (8 waves), 512 blocks
// -> 2 blocks/CU, 16 waves/CU (2x round 10). Thread owns 2 consecutive v for
// both rows: float2 EkT loads (512B/wave contiguous), 4 rcp chains.
// Software-pipelined 4-batch: 8 independent loads in flight.
//   score[v] = sumV - 2 * sum_a v_a / (Eq[a]*EkT[a,v] + 1)
// ---------------------------------------------------------------------------
__global__ __launch_bounds__(512, 4) void score_softmax_kernel(
    const float* __restrict__ Eq, const float* __restrict__ EkT,
    const float* __restrict__ attn_v, const int* __restrict__ mask,
    float* __restrict__ attn) {
  __shared__ float redA[8], redB[8];
  __shared__ float bc[4];

  int tid = threadIdx.x;
  int v0  = (tid & 63) * 2 + (tid >> 6) * 128;  // wave-contiguous float2
  int r0  = blockIdx.x * 2;
  int b   = r0 >> 8;               // TQ == 256

  const float* eqA = Eq + (size_t)r0 * A;
  const float* eqB = eqA + A;

  float sumV = 0.f;
#pragma unroll 16
  for (int i = 0; i < A; ++i) sumV += attn_v[i];

  const float* ekb = EkT + (size_t)b * A * TV + v0;
  float2 tA = make_float2(0.f, 0.f);
  float2 tB = make_float2(0.f, 0.f);

  // 4-batch software pipeline: c0..c3 current, n0..n3 next (8 in flight)
  float2 c0 = *(const float2*)(ekb + (size_t)0 * TV);
  float2 c1 = *(const float2*)(ekb + (size_t)1 * TV);
  float2 c2 = *(const float2*)(ekb + (size_t)2 * TV);
  float2 c3 = *(const float2*)(ekb + (size_t)3 * TV);

  for (int i = 0; i < A; i += 4) {
    float2 n0, n1, n2, n3;
    if (i < A - 4) {
      n0 = *(const float2*)(ekb + (size_t)(i + 4) * TV);
      n1 = *(const float2*)(ekb + (size_t)(i + 5) * TV);
      n2 = *(const float2*)(ekb + (size_t)(i + 6) * TV);
      n3 = *(const float2*)(ekb + (size_t)(i + 7) * TV);
    }
    float av0 = attn_v[i + 0], av1 = attn_v[i + 1];
    float av2 = attn_v[i + 2], av3 = attn_v[i + 3];
    float qa0 = eqA[i + 0], qa1 = eqA[i + 1], qa2 = eqA[i + 2], qa3 = eqA[i + 3];
    float qb0 = eqB[i + 0], qb1 = eqB[i + 1], qb2 = eqB[i + 2], qb3 = eqB[i + 3];

    tA.x = fmaf(av0, __builtin_amdgcn_rcpf(fmaf(c0.x, qa0, 1.f)), tA.x);
    tA.y = fmaf(av0, __builtin_amdgcn_rcpf(fmaf(c0.y, qa0, 1.f)), tA.y);
    tB.x = fmaf(av0, __builtin_amdgcn_rcpf(fmaf(c0.x, qb0, 1.f)), tB.x);
    tB.y = fmaf(av0, __builtin_amdgcn_rcpf(fmaf(c0.y, qb0, 1.f)), tB.y);

    tA.x = fmaf(av1, __builtin_amdgcn_rcpf(fmaf(c1.x, qa1, 1.f)), tA.x);
    tA.y = fmaf(av1, __builtin_amdgcn_rcpf(fmaf(c1.y, qa1, 1.f)), tA.y);
    tB.x = fmaf(av1, __builtin_amdgcn_rcpf(fmaf(c1.x, qb1, 1.f)), tB.x);
    tB.y = fmaf(av1, __builtin_amdgcn_rcpf(fmaf(c1.y, qb1, 1.f)), tB.y);

    tA.x = fmaf(av2, __builtin_amdgcn_rcpf(fmaf(c2.x, qa2, 1.f)), tA.x);
    tA.y = fmaf(av2, __builtin_amdgcn_rcpf(fmaf(c2.y, qa2, 1.f)), tA.y);
    tB.x = fmaf(av2, __builtin_amdgcn_rcpf(fmaf(c2.x, qb2, 1.f)), tB.x);
    tB.y = fmaf(av2, __builtin_amdgcn_rcpf(fmaf(c2.y, qb2, 1.f)), tB.y);

    tA.x = fmaf(av3, __builtin_amdgcn_rcpf(fmaf(c3.x, qa3, 1.f)), tA.x);
    tA.y = fmaf(av3, __builtin_amdgcn_rcpf(fmaf(c3.y, qa3, 1.f)), tA.y);
    tB.x = fmaf(av3, __builtin_amdgcn_rcpf(fmaf(c3.x, qb3, 1.f)), tB.x);
    tB.y = fmaf(av3, __builtin_amdgcn_rcpf(fmaf(c3.y, qb3, 1.f)), tB.y);

    c0 = n0; c1 = n1; c2 = n2; c3 = n3;
  }

  int2 mk = *(const int2*)(mask + b * TV + v0);
  float mkx = (1.f - (float)mk.x) * NEG_BIG_F;
  float mky = (1.f - (float)mk.y) * NEG_BIG_F;
  float2 sA, sB;
  sA.x = sumV - 2.f * tA.x + mkx;
  sA.y = sumV - 2.f * tA.y + mky;
  sB.x = sumV - 2.f * tB.x + mkx;
  sB.y = sumV - 2.f * tB.y + mky;

  float mA = fmaxf(sA.x, sA.y);
  float mB = fmaxf(sB.x, sB.y);
  for (int off = 32; off > 0; off >>= 1) {
    mA = fmaxf(mA, __shfl_down(mA, off, 64));
    mB = fmaxf(mB, __shfl_down(mB, off, 64));
  }
  int w = tid >> 6;
  if ((tid & 63) == 0) { redA[w] = mA; redB[w] = mB; }
  __syncthreads();
  if (tid == 0) {
    float a = redA[0], bm = redB[0];
#pragma unroll
    for (int i = 1; i < 8; ++i) { a = fmaxf(a, redA[i]); bm = fmaxf(bm, redB[i]); }
    bc[0] = a; bc[1] = bm;
  }
  __syncthreads();
  float MA = bc[0], MB = bc[1];

  float2 eAv, eBv;
  eAv.x = __builtin_amdgcn_exp2f((sA.x - MA) * LOG2E);
  eAv.y = __builtin_amdgcn_exp2f((sA.y - MA) * LOG2E);
  eBv.x = __builtin_amdgcn_exp2f((sB.x - MB) * LOG2E);
  eBv.y = __builtin_amdgcn_exp2f((sB.y - MB) * LOG2E);
  float lA = eAv.x + eAv.y;
  float lB = eBv.x + eBv.y;
  for (int off = 32; off > 0; off >>= 1) {
    lA += __shfl_down(lA, off, 64);
    lB += __shfl_down(lB, off, 64);
  }
  __syncthreads();   // protect red[] before rewrite
  if ((tid & 63) == 0) { redA[w] = lA; redB[w] = lB; }
  __syncthreads();
  if (tid == 0) {
    float a = 0.f, bs = 0.f;
#pragma unroll
    for (int i = 0; i < 8; ++i) { a += redA[i]; bs += redB[i]; }
    bc[2] = a; bc[3] = bs;
  }
  __syncthreads();
  float iA = 1.f / bc[2];
  float iB = 1.f / bc[3];

  *(float2*)(attn + (size_t)r0 * TV + v0) =
      make_float2(eAv.x * iA, eAv.y * iA);
  *(float2*)(attn + (size_t)(r0 + 1) * TV + v0) =
      make_float2(eBv.x * iB, eBv.y * iB);
}

// ---------------------------------------------------------------------------
// out[b,q,:] = sum_v attn[b,q,v] * inputs[b,v,:]   -- NO ATOMICS.
// (Round-8 exact version -- best measured pv config.)
// Block tile: 8 q x 128 d over the FULL v range; v-sum split across the 8
// waves (disjoint 128-v chunks), wave partials reduced through the 32 KB
// LDS buffer, plain coalesced store. grid (dt=4, qtile=128) = 512 blocks
// x 512 thr -> 2 blocks/CU, 16 waves/CU. Register tile 4q x 4d = 16 acc.
// ---------------------------------------------------------------------------
__global__ __launch_bounds__(512, 4) void pv_kernel(
    const float* __restrict__ attn, const float* __restrict__ X,
    float* __restrict__ out) {
  __shared__ float lds[8 * 1024];    // 32 KB: attn tile, then 8 partial tiles
  int dt = blockIdx.x;               // 0..3, d-slice of 128
  int q0 = blockIdx.y * 8;           // global row (b*TQ + q), 128 tiles
  int b  = q0 >> 8;                  // TQ == 256
  int tid  = threadIdx.x;
  int w    = tid >> 6;               // wave 0..7 -> v range [w*128, w*128+128)
  int lane = tid & 63;
  int col  = lane & 31;              // float4 d-column
  int qh   = lane >> 5;              // 0..1 -> q rows qh*4 .. qh*4+3
  int d0 = dt * 128 + col * 4;

  // stage attn tile: 8 rows x 1024 v (float4, coalesced)
  {
    const float4* src = (const float4*)(attn + (size_t)q0 * TV);
    float4* dst = (float4*)lds;
    for (int i = tid; i < 8 * 256; i += 512) dst[i] = src[i];
  }
  __syncthreads();

  float4 acc[4];
#pragma unroll
  for (int j = 0; j < 4; ++j) acc[j] = make_float4(0.f, 0.f, 0.f, 0.f);

  int vbase = w * 128;
  const float* Xb = X + ((size_t)b * TV + vbase) * D + d0;
  const float* arow = &lds[(qh * 4) * 1024 + vbase];  // 4 rows, stride 1024

  float4 xc0 = *(const float4*)(Xb + (size_t)0 * D);
  float4 xc1 = *(const float4*)(Xb + (size_t)1 * D);
  float4 xc2 = *(const float4*)(Xb + (size_t)2 * D);
  float4 xc3 = *(const float4*)(Xb + (size_t)3 * D);

  for (int vi = 0; vi < 128; vi += 4) {
    float4 xn0, xn1, xn2, xn3;
    if (vi < 124) {
      const float* Xn = Xb + (size_t)(vi + 4) * D;
      xn0 = *(const float4*)(Xn + (size_t)0 * D);
      xn1 = *(const float4*)(Xn + (size_t)1 * D);
      xn2 = *(const float4*)(Xn + (size_t)2 * D);
      xn3 = *(const float4*)(Xn + (size_t)3 * D);
    }
#pragma unroll
    for (int j = 0; j < 4; ++j) {
      float4 av = *(const float4*)(arow + j * 1024 + vi);  // 2-addr bcast
      acc[j].x = fmaf(av.x, xc0.x, acc[j].x);
      acc[j].y = fmaf(av.x, xc0.y, acc[j].y);
      acc[j].z = fmaf(av.x, xc0.z, acc[j].z);
      acc[j].w = fmaf(av.x, xc0.w, acc[j].w);
      acc[j].x = fmaf(av.y, xc1.x, acc[j].x);
      acc[j].y = fmaf(av.y, xc1.y, acc[j].y);
      acc[j].z = fmaf(av.y, xc1.z, acc[j].z);
      acc[j].w = fmaf(av.y, xc1.w, acc[j].w);
      acc[j].x = fmaf(av.z, xc2.x, acc[j].x);
      acc[j].y = fmaf(av.z, xc2.y, acc[j].y);
      acc[j].z = fmaf(av.z, xc2.z, acc[j].z);
      acc[j].w = fmaf(av.z, xc2.w, acc[j].w);
      acc[j].x = fmaf(av.w, xc3.x, acc[j].x);
      acc[j].y = fmaf(av.w, xc3.y, acc[j].y);
      acc[j].z = fmaf(av.w, xc3.z, acc[j].z);
      acc[j].w = fmaf(av.w, xc3.w, acc[j].w);
    }
    xc0 = xn0; xc1 = xn1; xc2 = xn2; xc3 = xn3;
  }

  __syncthreads();   // everyone done READING the attn tile

  // write wave partials: lds[w][8 rows][32 float4 cols]
  {
    float4* pat = (float4*)lds + (size_t)w * 256;
#pragma unroll
    for (int j = 0; j < 4; ++j)
      pat[(qh * 4 + j) * 32 + col] = acc[j];
  }
  __syncthreads();

  // reduce 8 partials and store: 256 float4 outputs
  if (tid < 256) {
    int row = tid >> 5;            // 0..7
    int c   = tid & 31;            // 0..31
    const float4* p = (const float4*)lds + tid;  // == row*32 + c
    float4 r = p[0];
#pragma unroll
    for (int i = 1; i < 8; ++i) {
      float4 t = p[(size_t)i * 256];
      r.x += t.x; r.y += t.y; r.z += t.z; r.w += t.w;
    }
    *(float4*)(out + (size_t)(q0 + row) * D + dt * 128 + c * 4) = r;
  }
}

extern "C" void kernel_launch(void* const* d_in, const int* in_sizes, int n_in,
                              void* d_out, int out_size, void* d_ws, size_t ws_size,
                              hipStream_t stream) {
  const float* inputs  = (const float*)d_in[0];  // [B,TV,D]
  const float* context = (const float*)d_in[1];  // [B,TQ,D]
  const int*   mask    = (const int*)d_in[2];    // [B,TV]
  const float* Wk      = (const float*)d_in[3];  // [D,A]
  const float* bk      = (const float*)d_in[4];  // [A]
  const float* Wq      = (const float*)d_in[5];  // [D,A]
  const float* bq      = (const float*)d_in[6];  // [A]
  const float* attn_v  = (const float*)d_in[7];  // [A]
  float* out = (float*)d_out;                    // [B,TQ,D]

  // Workspace layout (fp32): Eq | EkT | attn  = 0.5MB + 2MB + 4MB
  float* Eq   = (float*)d_ws;             // [B*TQ, A]
  float* EkT  = Eq + B * TQ * A;          // [B, A, TV]  (transposed!)
  float* attn = EkT + (size_t)B * A * TV; // [B*TQ, TV]

  proj_exp_kernel<<<QBLK + KBLK, 256, 0, stream>>>(context, inputs, Wq, bq,
                                                   Wk, bk, Eq, EkT);
  score_softmax_kernel<<<B * TQ / 2, 512, 0, stream>>>(Eq, EkT, attn_v, mask,
                                                       attn);
  pv_kernel<<<dim3(4, 128), 512, 0, stream>>>(attn, inputs, out);
}